// Round 2
// baseline (808.050 us; speedup 1.0000x reference)
//
#include <hip/hip_runtime.h>

// Causal MHA forward, B=4 S=2048 H=16 D=128, fp32 BSHD in/out.
// Transposed flash attention: S^T = K*Q^T so softmax state is per-lane scalar,
// and P^T (C-layout) feeds PV MFMA (16x16x16 B-operand) with ZERO data movement.
// Block = 128 q-rows x (b,h); 8 waves x 16 rows; BK=64 key tiles (4x16 chunks).

typedef short bf16x8 __attribute__((ext_vector_type(8)));
typedef short bf16x4 __attribute__((ext_vector_type(4)));
typedef short bf16x2 __attribute__((ext_vector_type(2)));
typedef float f32x4  __attribute__((ext_vector_type(4)));

#define SEQ 2048
#define NH  16
#define HD  128
#define BQ  128
#define BK  64
#define KSTR 136   // K tile row stride (bf16): 272B -> +4 banks/row, 2-way max on b128
#define VSTR 72    // V^T row stride (bf16): 144B -> +4 banks/row, 2-way max on b64

__device__ __forceinline__ short f2bf(float f) {  // RNE fp32 -> bf16 bits
  unsigned u = __builtin_bit_cast(unsigned, f);
  u = (u + 0x7FFFu + ((u >> 16) & 1u)) >> 16;
  return (short)u;
}

__global__ __launch_bounds__(512, 2) void fa_fwd(
    const float* __restrict__ Qg, const float* __restrict__ Kg,
    const float* __restrict__ Vg, float* __restrict__ Og)
{
  __shared__ __align__(16) short Klds[BK * KSTR];   // 17408 B
  __shared__ __align__(16) short Vtlds[HD * VSTR];  // 18432 B   (total 35840 B)

  const float qscale = 0.08838834764831845f * 1.4426950408889634f; // 1/sqrt(D)*log2e
  const int tid  = threadIdx.x;
  const int w    = tid >> 6;
  const int lane = tid & 63;
  const int L    = lane & 15;
  const int quad = lane >> 4;

  // bh fast-varying: heavy (qi=15) blocks spread across all XCDs first.
  const int bh = (int)blockIdx.x & 63;
  const int qi = 15 - ((int)blockIdx.x >> 6);
  const int bb = bh >> 4;
  const int hh = bh & 15;
  const int q0 = qi << 7;
  const int wrow0 = q0 + w * 16;     // this wave's 16 q-rows; this lane's row = wrow0+L

  // ---- Q fragment (B-operand): B[n=q=lane&15][k=quad*8+j], pre-scaled ----
  const float* qp = Qg + ((bb * SEQ + (wrow0 + L)) * NH + hh) * HD;
  bf16x8 bq[4];
#pragma unroll
  for (int dk = 0; dk < 4; ++dk) {
    const float4 a = *(const float4*)(qp + dk * 32 + quad * 8);
    const float4 b = *(const float4*)(qp + dk * 32 + quad * 8 + 4);
    bq[dk][0] = f2bf(a.x * qscale); bq[dk][1] = f2bf(a.y * qscale);
    bq[dk][2] = f2bf(a.z * qscale); bq[dk][3] = f2bf(a.w * qscale);
    bq[dk][4] = f2bf(b.x * qscale); bq[dk][5] = f2bf(b.y * qscale);
    bq[dk][6] = f2bf(b.z * qscale); bq[dk][7] = f2bf(b.w * qscale);
  }

  // O^T accumulator: O^T[d=dn*16+quad*4+r][q=lane&15]
  f32x4 O[8];
#pragma unroll
  for (int dn = 0; dn < 8; ++dn) O[dn] = (f32x4){0.f, 0.f, 0.f, 0.f};
  float m_r = -1e30f, l_r = 0.f;     // per-lane scalars (this lane's q-row)

  const int krow = tid >> 4;          // 0..31 (K stage row, V stage d-col group)
  const int kdp  = (tid & 15) << 3;   // 0..120
  const int vkp  = tid & 15;          // 0..15

  for (int kv0 = 0; kv0 < q0 + BQ; kv0 += BK) {
    // ---- stage K tile: row-major bf16 [key][d] ----
#pragma unroll
    for (int khh = 0; khh < 2; ++khh) {
      const int row = khh * 32 + krow;
      const float* kr = Kg + ((bb * SEQ + kv0 + row) * NH + hh) * HD + kdp;
      float4 k0 = *(const float4*)kr;
      float4 k1 = *(const float4*)(kr + 4);
      bf16x8 kb;
      kb[0] = f2bf(k0.x); kb[1] = f2bf(k0.y); kb[2] = f2bf(k0.z); kb[3] = f2bf(k0.w);
      kb[4] = f2bf(k1.x); kb[5] = f2bf(k1.y); kb[6] = f2bf(k1.z); kb[7] = f2bf(k1.w);
      *(bf16x8*)&Klds[row * KSTR + kdp] = kb;
    }
    // ---- stage V transposed: Vt[d][key], paired-key b32 writes ----
#pragma unroll
    for (int kh = 0; kh < 2; ++kh) {
      const float* vr = Vg + ((bb * SEQ + kv0 + kh * 32 + 2 * vkp) * NH + hh) * HD + krow * 4;
      float4 v0 = *(const float4*)vr;
      float4 v1 = *(const float4*)(vr + NH * HD);
      float f0[4] = {v0.x, v0.y, v0.z, v0.w};
      float f1[4] = {v1.x, v1.y, v1.z, v1.w};
#pragma unroll
      for (int i = 0; i < 4; ++i) {
        bf16x2 pr; pr[0] = f2bf(f0[i]); pr[1] = f2bf(f1[i]);
        *(bf16x2*)&Vtlds[(krow * 4 + i) * VSTR + kh * 32 + 2 * vkp] = pr;
      }
    }
    __syncthreads();

    const int rem = wrow0 + 16 - kv0;          // wave-uniform
    if (rem > 0) {
      const int nc = rem >= 64 ? 4 : ((rem + 15) >> 4);   // active 16-key chunks

      // ---- S^T = K Q^T : st[c][r] = S[q=lane&15][key=kv0+16c+quad*4+r] ----
      f32x4 st[4];
#pragma unroll
      for (int c = 0; c < 4; ++c) st[c] = (f32x4){0.f, 0.f, 0.f, 0.f};
#pragma unroll
      for (int dk = 0; dk < 4; ++dk) {
        for (int c = 0; c < nc; ++c) {
          bf16x8 ka = *(const bf16x8*)&Klds[(c * 16 + L) * KSTR + dk * 32 + quad * 8];
          st[c] = __builtin_amdgcn_mfma_f32_16x16x32_bf16(ka, bq[dk], st[c], 0, 0, 0);
        }
      }
      // ---- causal mask (wave-uniform test) ----
      const int myrow = wrow0 + L;
      if (kv0 + nc * 16 - 1 > wrow0) {
        for (int c = 0; c < nc; ++c) {
#pragma unroll
          for (int r = 0; r < 4; ++r) {
            if (kv0 + c * 16 + quad * 4 + r > myrow) st[c][r] = -1e30f;
          }
        }
      }
      // ---- online softmax: in-lane over regs, then shfl xor 16,32 ----
      float vmax = m_r;
      for (int c = 0; c < nc; ++c) {
        vmax = fmaxf(vmax, fmaxf(fmaxf(st[c][0], st[c][1]), fmaxf(st[c][2], st[c][3])));
      }
      vmax = fmaxf(vmax, __shfl_xor(vmax, 16));
      vmax = fmaxf(vmax, __shfl_xor(vmax, 32));
      const float al = __builtin_amdgcn_exp2f(m_r - vmax);
      m_r = vmax;

      bf16x4 pk[4];
      float rs = 0.f;
      for (int c = 0; c < nc; ++c) {
        float p0 = __builtin_amdgcn_exp2f(st[c][0] - vmax);
        float p1 = __builtin_amdgcn_exp2f(st[c][1] - vmax);
        float p2 = __builtin_amdgcn_exp2f(st[c][2] - vmax);
        float p3 = __builtin_amdgcn_exp2f(st[c][3] - vmax);
        rs += (p0 + p1) + (p2 + p3);
        pk[c][0] = f2bf(p0); pk[c][1] = f2bf(p1);
        pk[c][2] = f2bf(p2); pk[c][3] = f2bf(p3);
      }
      rs += __shfl_xor(rs, 16);
      rs += __shfl_xor(rs, 32);
      l_r = l_r * al + rs;

      // ---- rescale O^T (al is this lane's scalar) ----
#pragma unroll
      for (int dn = 0; dn < 8; ++dn) {
        O[dn][0] *= al; O[dn][1] *= al; O[dn][2] *= al; O[dn][3] *= al;
      }
      // ---- O^T += V^T P^T : A = Vt b64 frag, B = pk (C-layout IS B-layout) ----
      for (int c = 0; c < nc; ++c) {
#pragma unroll
        for (int dn = 0; dn < 8; ++dn) {
          bf16x4 va = *(const bf16x4*)&Vtlds[(dn * 16 + L) * VSTR + c * 16 + quad * 4];
          O[dn] = __builtin_amdgcn_mfma_f32_16x16x16bf16_1k(va, pk[c], O[dn], 0, 0, 0);
        }
      }
    }
    __syncthreads();
  }

  // ---- epilogue: O^T[d=dn*16+quad*4+r][q=L] -> Og row wrow0+L, float4 stores ----
  const float inv = 1.0f / l_r;
  float* op = Og + ((bb * SEQ + (wrow0 + L)) * NH + hh) * HD;
#pragma unroll
  for (int dn = 0; dn < 8; ++dn) {
    float4 ov;
    ov.x = O[dn][0] * inv; ov.y = O[dn][1] * inv;
    ov.z = O[dn][2] * inv; ov.w = O[dn][3] * inv;
    *(float4*)(op + dn * 16 + quad * 4) = ov;
  }
}

extern "C" void kernel_launch(void* const* d_in, const int* in_sizes, int n_in,
                              void* d_out, int out_size, void* d_ws, size_t ws_size,
                              hipStream_t stream) {
  const float* q = (const float*)d_in[0];
  const float* k = (const float*)d_in[1];
  const float* v = (const float*)d_in[2];
  float* o = (float*)d_out;
  dim3 grid(64 * (SEQ / BQ));   // 64 (b,h) x 16 q-tiles = 1024 blocks
  dim3 block(512);
  fa_fwd<<<grid, block, 0, stream>>>(q, k, v, o);
}

// Round 3
// 320.172 us; speedup vs baseline: 2.5238x; 2.5238x over previous
//
#include <hip/hip_runtime.h>

// Causal MHA forward, B=4 S=2048 H=16 D=128, fp32 BSHD in/out.
// Transposed flash attention: S^T = K*Q^T -> softmax state is a per-lane scalar,
// P^T (MFMA C-layout) feeds PV (16x16x16 B-operand) with zero data movement.
// R3 fix vs R2: ALL loops compile-time bounded (R2's runtime `nc` loops demoted
// register arrays to scratch: SGPR 112, +40MB FETCH, VALUBusy 70%).
// Block = 128 q-rows x (b,h); 8 waves x 16 rows; BK=64 key tiles (4x16 chunks).

typedef short bf16x8 __attribute__((ext_vector_type(8)));
typedef short bf16x4 __attribute__((ext_vector_type(4)));
typedef float f32x4  __attribute__((ext_vector_type(4)));
typedef unsigned u32x4 __attribute__((ext_vector_type(4)));
typedef unsigned u32x2 __attribute__((ext_vector_type(2)));

#define SEQ 2048
#define NH  16
#define HD  128
#define BQ  128
#define BK  64
#define KSTR 136   // K tile row stride (bf16): 272B
#define VSTR 72    // V^T row stride (bf16): 144B

// pack 2 fp32 -> bf16 pair (round-half-up: <=1ulp vs RNE, 2.5 VALU ops / 2 elems)
__device__ __forceinline__ unsigned pkbf(float a, float b) {
  unsigned ua = __builtin_bit_cast(unsigned, a);
  unsigned ub = __builtin_bit_cast(unsigned, b);
  return ((ua + 0x8000u) >> 16) | ((ub + 0x8000u) & 0xFFFF0000u);
}

__global__ __launch_bounds__(512, 4) void fa_fwd(
    const float* __restrict__ Qg, const float* __restrict__ Kg,
    const float* __restrict__ Vg, float* __restrict__ Og)
{
  __shared__ __align__(16) short Klds[BK * KSTR];   // 17408 B
  __shared__ __align__(16) short Vtlds[HD * VSTR];  // 18432 B

  const float qscale = 0.08838834764831845f * 1.4426950408889634f; // 1/sqrt(D)*log2e
  const int tid  = threadIdx.x;
  const int w    = tid >> 6;
  const int lane = tid & 63;
  const int L    = lane & 15;
  const int quad = lane >> 4;

  const int bh = (int)blockIdx.x & 63;           // bh fast: spreads across XCDs
  const int qi = 15 - ((int)blockIdx.x >> 6);    // heavy q-tiles first
  const int bb = bh >> 4;
  const int hh = bh & 15;
  const int q0 = qi << 7;
  const int wrow0 = q0 + w * 16;                 // this lane's q-row = wrow0 + L
  const int myrow = wrow0 + L;

  // ---- Q fragment (B-operand): B[n=q=L][k=quad*8+j], pre-scaled ----
  const float* qp = Qg + ((bb * SEQ + myrow) * NH + hh) * HD;
  bf16x8 bq[4];
#pragma unroll
  for (int dk = 0; dk < 4; ++dk) {
    const float4 a = *(const float4*)(qp + dk * 32 + quad * 8);
    const float4 b = *(const float4*)(qp + dk * 32 + quad * 8 + 4);
    u32x4 t;
    t[0] = pkbf(a.x * qscale, a.y * qscale);
    t[1] = pkbf(a.z * qscale, a.w * qscale);
    t[2] = pkbf(b.x * qscale, b.y * qscale);
    t[3] = pkbf(b.z * qscale, b.w * qscale);
    bq[dk] = __builtin_bit_cast(bf16x8, t);
  }

  // O^T accumulator: O^T[d=dn*16+quad*4+r][q=L]
  f32x4 O[8];
#pragma unroll
  for (int dn = 0; dn < 8; ++dn) O[dn] = (f32x4){0.f, 0.f, 0.f, 0.f};
  float m_r = -1e30f, l_r = 0.f;

  const int krow = tid >> 4;          // 0..31
  const int kdp  = (tid & 15) << 3;   // 0..120
  const int vkp  = tid & 15;          // 0..15

  for (int kv0 = 0; kv0 < q0 + BQ; kv0 += BK) {
    // ---- stage K tile: row-major bf16 [key][d], one b128 write per half ----
#pragma unroll
    for (int khh = 0; khh < 2; ++khh) {
      const int row = khh * 32 + krow;
      const float* kr = Kg + ((bb * SEQ + kv0 + row) * NH + hh) * HD + kdp;
      float4 k0 = *(const float4*)kr;
      float4 k1 = *(const float4*)(kr + 4);
      u32x4 kb;
      kb[0] = pkbf(k0.x, k0.y); kb[1] = pkbf(k0.z, k0.w);
      kb[2] = pkbf(k1.x, k1.y); kb[3] = pkbf(k1.z, k1.w);
      *(u32x4*)&Klds[row * KSTR + kdp] = kb;
    }
    // ---- stage V transposed: Vt[d][key], paired-key b32 writes ----
#pragma unroll
    for (int kh = 0; kh < 2; ++kh) {
      const float* vr = Vg + ((bb * SEQ + kv0 + kh * 32 + 2 * vkp) * NH + hh) * HD + krow * 4;
      float4 v0 = *(const float4*)vr;
      float4 v1 = *(const float4*)(vr + NH * HD);
      const float f0[4] = {v0.x, v0.y, v0.z, v0.w};
      const float f1[4] = {v1.x, v1.y, v1.z, v1.w};
#pragma unroll
      for (int i = 0; i < 4; ++i) {
        *(unsigned*)&Vtlds[(krow * 4 + i) * VSTR + kh * 32 + 2 * vkp] = pkbf(f0[i], f1[i]);
      }
    }
    __syncthreads();

    if (wrow0 + 16 > kv0) {   // wave-uniform: wave has rows >= kv0 (wrow0 >= kv0)
      // ---- S^T: st[c][r] = S[q=L][key=kv0+16c+quad*4+r] ----
      f32x4 st[4];
#pragma unroll
      for (int c = 0; c < 4; ++c) st[c] = (f32x4){0.f, 0.f, 0.f, 0.f};
#pragma unroll
      for (int dk = 0; dk < 4; ++dk) {
#pragma unroll
        for (int c = 0; c < 4; ++c) {
          bf16x8 ka = *(const bf16x8*)&Klds[(c * 16 + L) * KSTR + dk * 32 + quad * 8];
          st[c] = __builtin_amdgcn_mfma_f32_16x16x32_bf16(ka, bq[dk], st[c], 0, 0, 0);
        }
      }
      // ---- causal mask (only when tile crosses this wave's diagonal) ----
      if (kv0 + BK - 1 > wrow0) {
#pragma unroll
        for (int c = 0; c < 4; ++c) {
#pragma unroll
          for (int r = 0; r < 4; ++r) {
            if (kv0 + c * 16 + quad * 4 + r > myrow) st[c][r] = -1e30f;
          }
        }
      }
      // ---- online softmax: in-lane reduce, then xor-16/32 (cross-quad) ----
      float vmax = m_r;
#pragma unroll
      for (int c = 0; c < 4; ++c)
        vmax = fmaxf(vmax, fmaxf(fmaxf(st[c][0], st[c][1]), fmaxf(st[c][2], st[c][3])));
      vmax = fmaxf(vmax, __shfl_xor(vmax, 16));
      vmax = fmaxf(vmax, __shfl_xor(vmax, 32));
      const float al = __builtin_amdgcn_exp2f(m_r - vmax);
      m_r = vmax;

      bf16x4 pk[4];
      float rs = 0.f;
#pragma unroll
      for (int c = 0; c < 4; ++c) {
        const float p0 = __builtin_amdgcn_exp2f(st[c][0] - vmax);
        const float p1 = __builtin_amdgcn_exp2f(st[c][1] - vmax);
        const float p2 = __builtin_amdgcn_exp2f(st[c][2] - vmax);
        const float p3 = __builtin_amdgcn_exp2f(st[c][3] - vmax);
        rs += (p0 + p1) + (p2 + p3);
        u32x2 pu; pu[0] = pkbf(p0, p1); pu[1] = pkbf(p2, p3);
        pk[c] = __builtin_bit_cast(bf16x4, pu);
      }
      rs += __shfl_xor(rs, 16);
      rs += __shfl_xor(rs, 32);
      l_r = l_r * al + rs;

      // ---- rescale O^T ----
#pragma unroll
      for (int dn = 0; dn < 8; ++dn) {
        O[dn][0] *= al; O[dn][1] *= al; O[dn][2] *= al; O[dn][3] *= al;
      }
      // ---- O^T += V^T P^T : A = Vt b64 frag, B = pk (C-layout IS B-layout) ----
#pragma unroll
      for (int c = 0; c < 4; ++c) {
#pragma unroll
        for (int dn = 0; dn < 8; ++dn) {
          bf16x4 va = *(const bf16x4*)&Vtlds[(dn * 16 + L) * VSTR + c * 16 + quad * 4];
          O[dn] = __builtin_amdgcn_mfma_f32_16x16x16bf16_1k(va, pk[c], O[dn], 0, 0, 0);
        }
      }
    }
    __syncthreads();
  }

  // ---- epilogue: O^T[d=dn*16+quad*4+r][q=L] -> row wrow0+L, float4 stores ----
  const float inv = 1.0f / l_r;
  float* op = Og + ((bb * SEQ + myrow) * NH + hh) * HD;
#pragma unroll
  for (int dn = 0; dn < 8; ++dn) {
    float4 ov;
    ov.x = O[dn][0] * inv; ov.y = O[dn][1] * inv;
    ov.z = O[dn][2] * inv; ov.w = O[dn][3] * inv;
    *(float4*)(op + dn * 16 + quad * 4) = ov;
  }
}

extern "C" void kernel_launch(void* const* d_in, const int* in_sizes, int n_in,
                              void* d_out, int out_size, void* d_ws, size_t ws_size,
                              hipStream_t stream) {
  const float* q = (const float*)d_in[0];
  const float* k = (const float*)d_in[1];
  const float* v = (const float*)d_in[2];
  float* o = (float*)d_out;
  dim3 grid(64 * (SEQ / BQ));   // 64 (b,h) x 16 q-tiles = 1024 blocks
  dim3 block(512);
  fa_fwd<<<grid, block, 0, stream>>>(q, k, v, o);
}